// Round 1
// baseline (8927.557 us; speedup 1.0000x reference)
//
#include <hip/hip_runtime.h>

#define N 50000
#define E 800000
#define H 128
#define G 64
#define OUTC 10
#define L 6
#define EPS 1e-5f

__device__ __forceinline__ void atomAddF(float* p, float v) {
  unsafeAtomicAdd(p, v);   // hw global_atomic_add_f32 on gfx950
}

// ---------------- init ----------------
__global__ void zero_kernel(float* __restrict__ p, int n) {
  int i = blockIdx.x * blockDim.x + threadIdx.x;
  if (i < n) p[i] = 0.0f;
}

__global__ void deg_count_kernel(const int* __restrict__ dst, int* __restrict__ deg) {
  int e = blockIdx.x * blockDim.x + threadIdx.x;
  if (e < E) atomicAdd(&deg[dst[e]], 1);
}

__global__ void dinv_kernel(const int* __restrict__ deg, float* __restrict__ dinv) {
  int n = blockIdx.x * blockDim.x + threadIdx.x;
  if (n < N) dinv[n] = rsqrtf((float)(deg[n] + 1));
}

// ---------------- per-layer GEMM: hW = h@W ; agg = hW*selfw + bias ----------------
// block: 256 threads, tile 32 rows x 128 cols, 4x4 per thread
__global__ __launch_bounds__(256) void gemm_layer_kernel(
    const float* __restrict__ hin, const float* __restrict__ W,
    const float* __restrict__ bias, const float* __restrict__ dinv,
    float* __restrict__ hW, float* __restrict__ agg)
{
  __shared__ float hsT[128][36];  // [k][row], padded
  __shared__ float Ws[32][132];   // [k][col], padded
  const int tid = threadIdx.x;
  const int row0 = blockIdx.x * 32;

  // stage 32x128 input tile, transposed
  for (int s = tid; s < 32 * 32; s += 256) {
    int r = s >> 5, k4 = (s & 31) * 4;
    float4 v = make_float4(0.f, 0.f, 0.f, 0.f);
    int row = row0 + r;
    if (row < N) v = *(const float4*)&hin[row * H + k4];
    hsT[k4 + 0][r] = v.x; hsT[k4 + 1][r] = v.y;
    hsT[k4 + 2][r] = v.z; hsT[k4 + 3][r] = v.w;
  }

  float acc[4][4] = {};
  const int rg = tid >> 5, cg = tid & 31;
  const int r0 = rg * 4, c0 = cg * 4;

  for (int kc = 0; kc < 4; ++kc) {
    __syncthreads();
    for (int s = tid; s < 32 * 32; s += 256) {
      int k = s >> 5, c4 = (s & 31) * 4;
      *(float4*)&Ws[k][c4] = *(const float4*)&W[(kc * 32 + k) * H + c4];
    }
    __syncthreads();
#pragma unroll
    for (int k = 0; k < 32; ++k) {
      float4 a = *(const float4*)&hsT[kc * 32 + k][r0];
      float4 w = *(const float4*)&Ws[k][c0];
      acc[0][0] += a.x * w.x; acc[0][1] += a.x * w.y; acc[0][2] += a.x * w.z; acc[0][3] += a.x * w.w;
      acc[1][0] += a.y * w.x; acc[1][1] += a.y * w.y; acc[1][2] += a.y * w.z; acc[1][3] += a.y * w.w;
      acc[2][0] += a.z * w.x; acc[2][1] += a.z * w.y; acc[2][2] += a.z * w.z; acc[2][3] += a.z * w.w;
      acc[3][0] += a.w * w.x; acc[3][1] += a.w * w.y; acc[3][2] += a.w * w.z; acc[3][3] += a.w * w.w;
    }
  }

  float4 bv = *(const float4*)&bias[c0];
#pragma unroll
  for (int i = 0; i < 4; ++i) {
    int row = row0 + r0 + i;
    if (row < N) {
      float sw = dinv[row]; sw = sw * sw;  // 1/deg
      float4 o = make_float4(acc[i][0], acc[i][1], acc[i][2], acc[i][3]);
      *(float4*)&hW[row * H + c0] = o;
      float4 a2 = make_float4(o.x * sw + bv.x, o.y * sw + bv.y,
                              o.z * sw + bv.z, o.w * sw + bv.w);
      *(float4*)&agg[row * H + c0] = a2;
    }
  }
}

// ---------------- edge scatter: agg[dst] += hW[src] * dinv[src]*dinv[dst] ----------------
// 32 threads per edge, float4 per thread
__global__ __launch_bounds__(256) void scatter_kernel(
    const float* __restrict__ hW, const int* __restrict__ src,
    const int* __restrict__ dst, const float* __restrict__ dinv,
    float* __restrict__ agg)
{
  int t = blockIdx.x * 256 + threadIdx.x;
  int e = t >> 5, ln = (t & 31) * 4;
  if (e < E) {
    int s = src[e], d = dst[e];
    float w = dinv[s] * dinv[d];
    float4 v = *(const float4*)&hW[s * H + ln];
    float* o = &agg[d * H + ln];
    atomAddF(o + 0, v.x * w);
    atomAddF(o + 1, v.y * w);
    atomAddF(o + 2, v.z * w);
    atomAddF(o + 3, v.w * w);
  }
}

// ---------------- batchnorm stats: sums[c], sums[128+c] over N rows ----------------
__global__ __launch_bounds__(256) void bn_stats_kernel(
    const float* __restrict__ a, float* __restrict__ sums)
{
  __shared__ float red[256];
  int tid = threadIdx.x;
  int c = tid & 127, half = tid >> 7;
  int r0 = blockIdx.x * 128;
  float s = 0.f, q = 0.f;
  for (int i = 0; i < 64; ++i) {
    int r = r0 + i * 2 + half;
    if (r < N) { float v = a[r * H + c]; s += v; q += v * v; }
  }
  red[tid] = s; __syncthreads();
  float s2 = (half == 0) ? s + red[tid + 128] : 0.f;
  __syncthreads();
  red[tid] = q; __syncthreads();
  if (half == 0) {
    float q2 = q + red[tid + 128];
    atomAddF(&sums[c], s2);
    atomAddF(&sums[128 + c], q2);
  }
}

// ---------------- normalize + relu ----------------
__global__ __launch_bounds__(256) void bn_norm_kernel(
    const float* __restrict__ a, const float* __restrict__ sums,
    const float* __restrict__ gamma, const float* __restrict__ beta,
    float* __restrict__ hout)
{
  int t = blockIdx.x * 256 + threadIdx.x;
  int n = t >> 5, c4 = (t & 31) * 4;
  if (n < N) {
    float4 v = *(const float4*)&a[n * H + c4];
    float4 sm = *(const float4*)&sums[c4];
    float4 sq = *(const float4*)&sums[128 + c4];
    float4 ga = *(const float4*)&gamma[c4];
    float4 be = *(const float4*)&beta[c4];
    const float invN = 1.0f / (float)N;
    float4 o;
    {
      float mu = sm.x * invN; float var = sq.x * invN - mu * mu;
      o.x = fmaxf((v.x - mu) * rsqrtf(var + EPS) * ga.x + be.x, 0.f);
    }
    {
      float mu = sm.y * invN; float var = sq.y * invN - mu * mu;
      o.y = fmaxf((v.y - mu) * rsqrtf(var + EPS) * ga.y + be.y, 0.f);
    }
    {
      float mu = sm.z * invN; float var = sq.z * invN - mu * mu;
      o.z = fmaxf((v.z - mu) * rsqrtf(var + EPS) * ga.z + be.z, 0.f);
    }
    {
      float mu = sm.w * invN; float var = sq.w * invN - mu * mu;
      o.w = fmaxf((v.w - mu) * rsqrtf(var + EPS) * ga.w + be.w, 0.f);
    }
    *(float4*)&hout[n * H + c4] = o;
  }
}

// ---------------- global mean pool (accumulate) ----------------
__global__ __launch_bounds__(256) void pool_kernel(
    const float* __restrict__ h, const int* __restrict__ batch,
    float* __restrict__ pooled, float* __restrict__ cnt)
{
  int t = blockIdx.x * 256 + threadIdx.x;
  int n = t >> 5, c4 = (t & 31) * 4;
  if (n < N) {
    int g = batch[n];
    float4 v = *(const float4*)&h[n * H + c4];
    float* o = &pooled[g * H + c4];
    atomAddF(o + 0, v.x);
    atomAddF(o + 1, v.y);
    atomAddF(o + 2, v.z);
    atomAddF(o + 3, v.w);
    if ((t & 31) == 0) atomAddF(&cnt[g], 1.0f);
  }
}

// ---------------- head ----------------
__global__ void head1_kernel(const float* __restrict__ pooled, const float* __restrict__ cnt,
                             const float* __restrict__ W1, const float* __restrict__ b1,
                             float* __restrict__ z1)
{
  int t = blockIdx.x * 256 + threadIdx.x;  // 8192
  int g = t >> 7, c = t & 127;
  float s = 0.f;
  for (int k = 0; k < H; ++k) s += pooled[g * H + k] * W1[k * H + c];
  z1[t] = s / fmaxf(cnt[g], 1.0f) + b1[c];
}

__global__ void head_bn_kernel(float* __restrict__ z1,
                               const float* __restrict__ gamma, const float* __restrict__ beta)
{
  int c = threadIdx.x;  // 128 threads
  float s = 0.f, q = 0.f;
  for (int g = 0; g < G; ++g) { float v = z1[g * H + c]; s += v; q += v * v; }
  float mu = s / (float)G;
  float var = q / (float)G - mu * mu;
  float rs = rsqrtf(var + EPS);
  float ga = gamma[c], be = beta[c];
  for (int g = 0; g < G; ++g) {
    float v = z1[g * H + c];
    z1[g * H + c] = fmaxf((v - mu) * rs * ga + be, 0.f);
  }
}

__global__ void head2_kernel(const float* __restrict__ z1, const float* __restrict__ W2,
                             const float* __restrict__ b2, float* __restrict__ z2)
{
  int t = blockIdx.x * 256 + threadIdx.x;  // 8192
  int g = t >> 7, c = t & 127;
  float s = b2[c];
  for (int k = 0; k < H; ++k) s += z1[g * H + k] * W2[k * H + c];
  z2[t] = fmaxf(s, 0.f);
}

__global__ void head3_kernel(const float* __restrict__ z2, const float* __restrict__ W3,
                             const float* __restrict__ b3, float* __restrict__ out)
{
  int t = blockIdx.x * 256 + threadIdx.x;
  if (t < G * OUTC) {
    int g = t / OUTC, o = t % OUTC;
    float s = b3[o];
    for (int k = 0; k < H; ++k) s += z2[g * H + k] * W3[k * OUTC + o];
    out[t] = s;
  }
}

extern "C" void kernel_launch(void* const* d_in, const int* in_sizes, int n_in,
                              void* d_out, int out_size, void* d_ws, size_t ws_size,
                              hipStream_t stream) {
  const float* x     = (const float*)d_in[0];
  const int*   ei    = (const int*)d_in[1];
  const int*   srcp  = ei;
  const int*   dstp  = ei + E;
  const int*   batch = (const int*)d_in[2];
  const float* convW = (const float*)d_in[3];
  const float* convb = (const float*)d_in[4];
  const float* bng   = (const float*)d_in[5];
  const float* bnb   = (const float*)d_in[6];
  const float* W1    = (const float*)d_in[7];
  const float* b1    = (const float*)d_in[8];
  const float* hg    = (const float*)d_in[9];
  const float* hb    = (const float*)d_in[10];
  const float* W2    = (const float*)d_in[11];
  const float* b2    = (const float*)d_in[12];
  const float* W3    = (const float*)d_in[13];
  const float* b3    = (const float*)d_in[14];
  float* out = (float*)d_out;

  float* ws     = (float*)d_ws;
  float* hW     = ws;               // N*H
  float* agg    = hW + (size_t)N * H;
  float* hbuf   = agg + (size_t)N * H;
  float* dinv   = hbuf + (size_t)N * H;
  int*   deg    = (int*)(dinv + N);           // zero region starts here
  float* pooled = (float*)(deg + N);          // G*H
  float* cnt    = pooled + G * H;             // G
  float* bnsums = cnt + G;                    // 5*256
  float* z1     = bnsums + (L - 1) * 256;     // G*H
  float* z2     = z1 + G * H;                 // G*H

  const int zero_words = N + G * H + G + (L - 1) * 256;
  zero_kernel<<<(zero_words + 255) / 256, 256, 0, stream>>>((float*)deg, zero_words);
  deg_count_kernel<<<(E + 255) / 256, 256, 0, stream>>>(dstp, deg);
  dinv_kernel<<<(N + 255) / 256, 256, 0, stream>>>(deg, dinv);

  const float* hin = x;
  for (int l = 0; l < L; ++l) {
    gemm_layer_kernel<<<(N + 31) / 32, 256, 0, stream>>>(
        hin, convW + (size_t)l * H * H, convb + (size_t)l * H, dinv, hW, agg);
    scatter_kernel<<<E * 32 / 256, 256, 0, stream>>>(hW, srcp, dstp, dinv, agg);
    if (l < L - 1) {
      bn_stats_kernel<<<(N + 127) / 128, 256, 0, stream>>>(agg, bnsums + l * 256);
      bn_norm_kernel<<<N * 32 / 256, 256, 0, stream>>>(
          agg, bnsums + l * 256, bng + (size_t)l * H, bnb + (size_t)l * H, hbuf);
      hin = hbuf;
    }
  }

  pool_kernel<<<N * 32 / 256, 256, 0, stream>>>(agg, batch, pooled, cnt);
  head1_kernel<<<32, 256, 0, stream>>>(pooled, cnt, W1, b1, z1);
  head_bn_kernel<<<1, 128, 0, stream>>>(z1, hg, hb);
  head2_kernel<<<32, 256, 0, stream>>>(z1, W2, b2, z2);
  head3_kernel<<<3, 256, 0, stream>>>(z2, W3, b3, out);
}

// Round 2
// 1103.212 us; speedup vs baseline: 8.0923x; 8.0923x over previous
//
#include <hip/hip_runtime.h>

#define N 50000
#define E 800000
#define H 128
#define G 64
#define OUTC 10
#define L 6
#define EPS 1e-5f

__device__ __forceinline__ void atomAddF(float* p, float v) {
  unsafeAtomicAdd(p, v);   // hw global_atomic_add_f32 on gfx950
}

// ---------------- init ----------------
__global__ void zero_kernel(int* __restrict__ p, int n) {
  int i = blockIdx.x * blockDim.x + threadIdx.x;
  if (i < n) p[i] = 0;
}

__global__ void deg_count_kernel(const int* __restrict__ dst, int* __restrict__ deg) {
  int e = blockIdx.x * blockDim.x + threadIdx.x;
  if (e < E) atomicAdd(&deg[dst[e]], 1);
}

__global__ void dinv_kernel(const int* __restrict__ deg, float* __restrict__ dinv) {
  int n = blockIdx.x * blockDim.x + threadIdx.x;
  if (n < N) dinv[n] = rsqrtf((float)(deg[n] + 1));
}

// exclusive scan of deg[N] -> rowptr[N+1], single block of 1024 threads
__global__ __launch_bounds__(1024) void scan_kernel(const int* __restrict__ deg,
                                                    int* __restrict__ rowptr) {
  __shared__ int part[1024];
  const int tid = threadIdx.x;
  const int CH = (N + 1023) / 1024;  // 49
  int base = tid * CH;
  int lim = min(base + CH, N);
  int s = 0;
  for (int i = base; i < lim; ++i) s += deg[i];
  part[tid] = s;
  __syncthreads();
  // Hillis-Steele inclusive scan
  for (int off = 1; off < 1024; off <<= 1) {
    int v = (tid >= off) ? part[tid - off] : 0;
    __syncthreads();
    part[tid] += v;
    __syncthreads();
  }
  int run = (tid == 0) ? 0 : part[tid - 1];
  for (int i = base; i < lim; ++i) { rowptr[i] = run; run += deg[i]; }
  if (tid == 1023) rowptr[N] = part[1023];
}

// fill CSR: for each edge, slot at rowptr[dst]+cursor; pack (src, weight)
__global__ void csr_fill_kernel(const int* __restrict__ src, const int* __restrict__ dst,
                                const float* __restrict__ dinv, const int* __restrict__ rowptr,
                                int* __restrict__ cursor, int2* __restrict__ csr) {
  int e = blockIdx.x * blockDim.x + threadIdx.x;
  if (e < E) {
    int s = src[e], d = dst[e];
    int pos = rowptr[d] + atomicAdd(&cursor[d], 1);
    float w = dinv[s] * dinv[d];
    csr[pos] = make_int2(s, __float_as_int(w));
  }
}

// ---------------- per-layer GEMM: hW = f(hin)@W ----------------
// f = identity (bnsums==null) or BN+ReLU fused on load
// block: 256 threads, tile 32 rows x 128 cols, 4x4 per thread
__global__ __launch_bounds__(256) void gemm_layer_kernel(
    const float* __restrict__ hin, const float* __restrict__ W,
    float* __restrict__ hW,
    const float* __restrict__ bnsums, const float* __restrict__ gamma,
    const float* __restrict__ beta)
{
  __shared__ float hsT[128][36];  // [k][row], padded
  __shared__ float Ws[32][132];   // [k][col], padded
  const int tid = threadIdx.x;
  const int row0 = blockIdx.x * 32;
  const float invN = 1.0f / (float)N;

  // stage 32x128 input tile, transposed, with optional fused BN+ReLU
  for (int s = tid; s < 32 * 32; s += 256) {
    int r = s >> 5, k4 = (s & 31) * 4;
    float4 v = make_float4(0.f, 0.f, 0.f, 0.f);
    int row = row0 + r;
    if (row < N) v = *(const float4*)&hin[row * H + k4];
    if (bnsums) {
      float4 sm = *(const float4*)&bnsums[k4];
      float4 sq = *(const float4*)&bnsums[128 + k4];
      float4 ga = *(const float4*)&gamma[k4];
      float4 be = *(const float4*)&beta[k4];
      float mu, var;
      mu = sm.x * invN; var = sq.x * invN - mu * mu;
      v.x = fmaxf((v.x - mu) * rsqrtf(var + EPS) * ga.x + be.x, 0.f);
      mu = sm.y * invN; var = sq.y * invN - mu * mu;
      v.y = fmaxf((v.y - mu) * rsqrtf(var + EPS) * ga.y + be.y, 0.f);
      mu = sm.z * invN; var = sq.z * invN - mu * mu;
      v.z = fmaxf((v.z - mu) * rsqrtf(var + EPS) * ga.z + be.z, 0.f);
      mu = sm.w * invN; var = sq.w * invN - mu * mu;
      v.w = fmaxf((v.w - mu) * rsqrtf(var + EPS) * ga.w + be.w, 0.f);
    }
    hsT[k4 + 0][r] = v.x; hsT[k4 + 1][r] = v.y;
    hsT[k4 + 2][r] = v.z; hsT[k4 + 3][r] = v.w;
  }

  float acc[4][4] = {};
  const int rg = tid >> 5, cg = tid & 31;
  const int r0 = rg * 4, c0 = cg * 4;

  for (int kc = 0; kc < 4; ++kc) {
    __syncthreads();
    for (int s = tid; s < 32 * 32; s += 256) {
      int k = s >> 5, c4 = (s & 31) * 4;
      *(float4*)&Ws[k][c4] = *(const float4*)&W[(kc * 32 + k) * H + c4];
    }
    __syncthreads();
#pragma unroll
    for (int k = 0; k < 32; ++k) {
      float4 a = *(const float4*)&hsT[kc * 32 + k][r0];
      float4 w = *(const float4*)&Ws[k][c0];
      acc[0][0] += a.x * w.x; acc[0][1] += a.x * w.y; acc[0][2] += a.x * w.z; acc[0][3] += a.x * w.w;
      acc[1][0] += a.y * w.x; acc[1][1] += a.y * w.y; acc[1][2] += a.y * w.z; acc[1][3] += a.y * w.w;
      acc[2][0] += a.z * w.x; acc[2][1] += a.z * w.y; acc[2][2] += a.z * w.z; acc[2][3] += a.z * w.w;
      acc[3][0] += a.w * w.x; acc[3][1] += a.w * w.y; acc[3][2] += a.w * w.z; acc[3][3] += a.w * w.w;
    }
  }

#pragma unroll
  for (int i = 0; i < 4; ++i) {
    int row = row0 + r0 + i;
    if (row < N)
      *(float4*)&hW[row * H + c0] = make_float4(acc[i][0], acc[i][1], acc[i][2], acc[i][3]);
  }
}

// ---------------- CSR gather: agg[n] = sum_e w_e*hW[src_e] + hW[n]/deg + bias ----------------
// 32 lanes per node, float4 per lane; no atomics
__global__ __launch_bounds__(256) void gather_kernel(
    const float* __restrict__ hW, const int2* __restrict__ csr,
    const int* __restrict__ rowptr, const float* __restrict__ dinv,
    const float* __restrict__ bias, float* __restrict__ agg)
{
  int t = blockIdx.x * 256 + threadIdx.x;
  int n = t >> 5, c4 = (t & 31) * 4;
  if (n >= N) return;
  float sw = dinv[n]; sw = sw * sw;  // 1/deg
  float4 self = *(const float4*)&hW[n * H + c4];
  float4 bv = *(const float4*)&bias[c4];
  float4 acc = make_float4(self.x * sw + bv.x, self.y * sw + bv.y,
                           self.z * sw + bv.z, self.w * sw + bv.w);
  int e = rowptr[n], end = rowptr[n + 1];
  for (; e + 1 < end; e += 2) {
    int2 p0 = csr[e], p1 = csr[e + 1];
    float w0 = __int_as_float(p0.y), w1 = __int_as_float(p1.y);
    float4 v0 = *(const float4*)&hW[p0.x * H + c4];
    float4 v1 = *(const float4*)&hW[p1.x * H + c4];
    acc.x += w0 * v0.x + w1 * v1.x;
    acc.y += w0 * v0.y + w1 * v1.y;
    acc.z += w0 * v0.z + w1 * v1.z;
    acc.w += w0 * v0.w + w1 * v1.w;
  }
  if (e < end) {
    int2 p0 = csr[e];
    float w0 = __int_as_float(p0.y);
    float4 v0 = *(const float4*)&hW[p0.x * H + c4];
    acc.x += w0 * v0.x; acc.y += w0 * v0.y;
    acc.z += w0 * v0.z; acc.w += w0 * v0.w;
  }
  *(float4*)&agg[n * H + c4] = acc;
}

// ---------------- batchnorm stats: sums[c], sums[128+c] over N rows ----------------
__global__ __launch_bounds__(256) void bn_stats_kernel(
    const float* __restrict__ a, float* __restrict__ sums)
{
  __shared__ float red[256];
  int tid = threadIdx.x;
  int c = tid & 127, half = tid >> 7;
  int r0 = blockIdx.x * 128;
  float s = 0.f, q = 0.f;
  for (int i = 0; i < 64; ++i) {
    int r = r0 + i * 2 + half;
    if (r < N) { float v = a[r * H + c]; s += v; q += v * v; }
  }
  red[tid] = s; __syncthreads();
  float s2 = (half == 0) ? s + red[tid + 128] : 0.f;
  __syncthreads();
  red[tid] = q; __syncthreads();
  if (half == 0) {
    float q2 = q + red[tid + 128];
    atomAddF(&sums[c], s2);
    atomAddF(&sums[128 + c], q2);
  }
}

// ---------------- global mean pool: batch is sorted -> binary search segment ----------------
__global__ __launch_bounds__(256) void pool_kernel(
    const float* __restrict__ h, const int* __restrict__ batch,
    float* __restrict__ pooled, float* __restrict__ cnt)
{
  __shared__ float red[256];
  int g = blockIdx.x;
  int tid = threadIdx.x;
  // lower bounds of g and g+1 in sorted batch[]
  int lo = 0, hi = N;
  while (lo < hi) { int m = (lo + hi) >> 1; if (batch[m] < g) lo = m + 1; else hi = m; }
  int lo2 = lo, hi2 = N;
  while (lo2 < hi2) { int m = (lo2 + hi2) >> 1; if (batch[m] < g + 1) lo2 = m + 1; else hi2 = m; }
  int c = tid & 127, half = tid >> 7;
  float s = 0.f;
  for (int n = lo + half; n < lo2; n += 2) s += h[n * H + c];
  red[tid] = s; __syncthreads();
  if (half == 0) {
    pooled[g * H + c] = s + red[tid + 128];
    if (c == 0) cnt[g] = (float)(lo2 - lo);
  }
}

// ---------------- head ----------------
__global__ void head1_kernel(const float* __restrict__ pooled, const float* __restrict__ cnt,
                             const float* __restrict__ W1, const float* __restrict__ b1,
                             float* __restrict__ z1)
{
  int t = blockIdx.x * 256 + threadIdx.x;  // 8192
  int g = t >> 7, c = t & 127;
  float s = 0.f;
  for (int k = 0; k < H; ++k) s += pooled[g * H + k] * W1[k * H + c];
  z1[t] = s / fmaxf(cnt[g], 1.0f) + b1[c];
}

__global__ void head_bn_kernel(float* __restrict__ z1,
                               const float* __restrict__ gamma, const float* __restrict__ beta)
{
  int c = threadIdx.x;  // 128 threads
  float s = 0.f, q = 0.f;
  for (int g = 0; g < G; ++g) { float v = z1[g * H + c]; s += v; q += v * v; }
  float mu = s / (float)G;
  float var = q / (float)G - mu * mu;
  float rs = rsqrtf(var + EPS);
  float ga = gamma[c], be = beta[c];
  for (int g = 0; g < G; ++g) {
    float v = z1[g * H + c];
    z1[g * H + c] = fmaxf((v - mu) * rs * ga + be, 0.f);
  }
}

__global__ void head2_kernel(const float* __restrict__ z1, const float* __restrict__ W2,
                             const float* __restrict__ b2, float* __restrict__ z2)
{
  int t = blockIdx.x * 256 + threadIdx.x;  // 8192
  int g = t >> 7, c = t & 127;
  float s = b2[c];
  for (int k = 0; k < H; ++k) s += z1[g * H + k] * W2[k * H + c];
  z2[t] = fmaxf(s, 0.f);
}

__global__ void head3_kernel(const float* __restrict__ z2, const float* __restrict__ W3,
                             const float* __restrict__ b3, float* __restrict__ out)
{
  int t = blockIdx.x * 256 + threadIdx.x;
  if (t < G * OUTC) {
    int g = t / OUTC, o = t % OUTC;
    float s = b3[o];
    for (int k = 0; k < H; ++k) s += z2[g * H + k] * W3[k * OUTC + o];
    out[t] = s;
  }
}

extern "C" void kernel_launch(void* const* d_in, const int* in_sizes, int n_in,
                              void* d_out, int out_size, void* d_ws, size_t ws_size,
                              hipStream_t stream) {
  const float* x     = (const float*)d_in[0];
  const int*   ei    = (const int*)d_in[1];
  const int*   srcp  = ei;
  const int*   dstp  = ei + E;
  const int*   batch = (const int*)d_in[2];
  const float* convW = (const float*)d_in[3];
  const float* convb = (const float*)d_in[4];
  const float* bng   = (const float*)d_in[5];
  const float* bnb   = (const float*)d_in[6];
  const float* W1    = (const float*)d_in[7];
  const float* b1    = (const float*)d_in[8];
  const float* hg    = (const float*)d_in[9];
  const float* hb    = (const float*)d_in[10];
  const float* W2    = (const float*)d_in[11];
  const float* b2    = (const float*)d_in[12];
  const float* W3    = (const float*)d_in[13];
  const float* b3    = (const float*)d_in[14];
  float* out = (float*)d_out;

  float* ws     = (float*)d_ws;
  float* hW     = ws;                            // N*H
  float* agg    = hW + (size_t)N * H;            // N*H
  float* dinv   = agg + (size_t)N * H;           // N
  int*   rowptr = (int*)(dinv + N);              // N+2 (pad for int2 align)
  int2*  csr    = (int2*)(rowptr + N + 2);       // E
  int*   deg    = (int*)(csr + E);               // N   <- zero region start
  int*   cursor = deg + N;                       // N
  float* bnsums = (float*)(cursor + N);          // (L-1)*256
  float* pooled = bnsums + (L - 1) * 256;        // G*H
  float* cnt    = pooled + G * H;                // G
  float* z1     = cnt + G;                       // G*H
  float* z2     = z1 + G * H;                    // G*H

  const int zero_words = N + N + (L - 1) * 256;
  zero_kernel<<<(zero_words + 255) / 256, 256, 0, stream>>>(deg, zero_words);
  deg_count_kernel<<<(E + 255) / 256, 256, 0, stream>>>(dstp, deg);
  dinv_kernel<<<(N + 255) / 256, 256, 0, stream>>>(deg, dinv);
  scan_kernel<<<1, 1024, 0, stream>>>(deg, rowptr);
  csr_fill_kernel<<<(E + 255) / 256, 256, 0, stream>>>(srcp, dstp, dinv, rowptr, cursor, csr);

  const float* hin = x;
  for (int l = 0; l < L; ++l) {
    const float* bs = (l == 0) ? nullptr : bnsums + (l - 1) * 256;
    const float* ga = (l == 0) ? nullptr : bng + (size_t)(l - 1) * H;
    const float* be = (l == 0) ? nullptr : bnb + (size_t)(l - 1) * H;
    gemm_layer_kernel<<<(N + 31) / 32, 256, 0, stream>>>(
        hin, convW + (size_t)l * H * H, hW, bs, ga, be);
    gather_kernel<<<N * 32 / 256, 256, 0, stream>>>(
        hW, csr, rowptr, dinv, convb + (size_t)l * H, agg);
    if (l < L - 1) {
      bn_stats_kernel<<<(N + 127) / 128, 256, 0, stream>>>(agg, bnsums + l * 256);
      hin = agg;
    }
  }

  pool_kernel<<<G, 256, 0, stream>>>(agg, batch, pooled, cnt);
  head1_kernel<<<32, 256, 0, stream>>>(pooled, cnt, W1, b1, z1);
  head_bn_kernel<<<1, 128, 0, stream>>>(z1, hg, hb);
  head2_kernel<<<32, 256, 0, stream>>>(z1, W2, b2, z2);
  head3_kernel<<<3, 256, 0, stream>>>(z2, W3, b3, out);
}

// Round 3
// 942.413 us; speedup vs baseline: 9.4731x; 1.1706x over previous
//
#include <hip/hip_runtime.h>

#define N 50000
#define E 800000
#define H 128
#define G 64
#define OUTC 10
#define L 6
#define EPS 1e-5f

typedef unsigned short ushort_t;

__device__ __forceinline__ void atomAddF(float* p, float v) {
  unsafeAtomicAdd(p, v);   // hw global_atomic_add_f32 on gfx950
}

__device__ __forceinline__ unsigned short f2bf(float f) {
  unsigned u = __float_as_uint(f);
  unsigned r = (u + 0x7FFF + ((u >> 16) & 1)) >> 16;  // RNE
  return (unsigned short)r;
}
__device__ __forceinline__ float bf2f(unsigned short b) {
  return __uint_as_float(((unsigned)b) << 16);
}

// ---------------- init ----------------
__global__ void zero_kernel(int* __restrict__ p, int n) {
  int i = blockIdx.x * blockDim.x + threadIdx.x;
  if (i < n) p[i] = 0;
}

__global__ void deg_count_kernel(const int* __restrict__ dst, int* __restrict__ deg) {
  int e = blockIdx.x * blockDim.x + threadIdx.x;
  if (e < E) atomicAdd(&deg[dst[e]], 1);
}

__global__ void dinv_kernel(const int* __restrict__ deg, float* __restrict__ dinv) {
  int n = blockIdx.x * blockDim.x + threadIdx.x;
  if (n < N) dinv[n] = rsqrtf((float)(deg[n] + 1));
}

// exclusive scan of deg[N] -> rowptr[N+1], single block of 1024 threads
__global__ __launch_bounds__(1024) void scan_kernel(const int* __restrict__ deg,
                                                    int* __restrict__ rowptr) {
  __shared__ int part[1024];
  const int tid = threadIdx.x;
  const int CH = (N + 1023) / 1024;  // 49
  int base = tid * CH;
  int lim = min(base + CH, N);
  int s = 0;
  for (int i = base; i < lim; ++i) s += deg[i];
  part[tid] = s;
  __syncthreads();
  for (int off = 1; off < 1024; off <<= 1) {
    int v = (tid >= off) ? part[tid - off] : 0;
    __syncthreads();
    part[tid] += v;
    __syncthreads();
  }
  int run = (tid == 0) ? 0 : part[tid - 1];
  for (int i = base; i < lim; ++i) { rowptr[i] = run; run += deg[i]; }
  if (tid == 1023) rowptr[N] = part[1023];
}

__global__ void csr_fill_kernel(const int* __restrict__ src, const int* __restrict__ dst,
                                const float* __restrict__ dinv, const int* __restrict__ rowptr,
                                int* __restrict__ cursor, int2* __restrict__ csr) {
  int e = blockIdx.x * blockDim.x + threadIdx.x;
  if (e < E) {
    int s = src[e], d = dst[e];
    int pos = rowptr[d] + atomicAdd(&cursor[d], 1);
    float w = dinv[s] * dinv[d];
    csr[pos] = make_int2(s, __float_as_int(w));
  }
}

// ---------------- per-layer GEMM: hW_bf16 = f(hin)@W ----------------
// f = identity (bnsums==null) or BN+ReLU fused on load
// block: 256 threads, tile 64 rows x 128 cols, 8x4 per thread
__global__ __launch_bounds__(256) void gemm_layer_kernel(
    const float* __restrict__ hin, const float* __restrict__ W,
    ushort_t* __restrict__ hWb,
    const float* __restrict__ bnsums, const float* __restrict__ gamma,
    const float* __restrict__ beta)
{
  __shared__ float hsT[128][68];  // [k][row], 64 rows + pad; (68*4)%16==0 keeps b128 align
  __shared__ float Ws[32][132];   // [k][col], padded
  const int tid = threadIdx.x;
  const int row0 = blockIdx.x * 64;
  const float invN = 1.0f / (float)N;

  // stage 64x128 input tile, transposed, with optional fused BN+ReLU
  for (int s = tid; s < 64 * 32; s += 256) {
    int r = s >> 5, k4 = (s & 31) * 4;
    float4 v = make_float4(0.f, 0.f, 0.f, 0.f);
    int row = row0 + r;
    if (row < N) v = *(const float4*)&hin[row * H + k4];
    if (bnsums) {
      float4 sm = *(const float4*)&bnsums[k4];
      float4 sq = *(const float4*)&bnsums[128 + k4];
      float4 ga = *(const float4*)&gamma[k4];
      float4 be = *(const float4*)&beta[k4];
      float mu, var;
      mu = sm.x * invN; var = sq.x * invN - mu * mu;
      v.x = fmaxf((v.x - mu) * rsqrtf(var + EPS) * ga.x + be.x, 0.f);
      mu = sm.y * invN; var = sq.y * invN - mu * mu;
      v.y = fmaxf((v.y - mu) * rsqrtf(var + EPS) * ga.y + be.y, 0.f);
      mu = sm.z * invN; var = sq.z * invN - mu * mu;
      v.z = fmaxf((v.z - mu) * rsqrtf(var + EPS) * ga.z + be.z, 0.f);
      mu = sm.w * invN; var = sq.w * invN - mu * mu;
      v.w = fmaxf((v.w - mu) * rsqrtf(var + EPS) * ga.w + be.w, 0.f);
    }
    hsT[k4 + 0][r] = v.x; hsT[k4 + 1][r] = v.y;
    hsT[k4 + 2][r] = v.z; hsT[k4 + 3][r] = v.w;
  }

  float acc[8][4] = {};
  const int rg = tid >> 5, cg = tid & 31;
  const int r0 = rg * 8, c0 = cg * 4;

  for (int kc = 0; kc < 4; ++kc) {
    __syncthreads();
    for (int s = tid; s < 32 * 32; s += 256) {
      int k = s >> 5, c4 = (s & 31) * 4;
      *(float4*)&Ws[k][c4] = *(const float4*)&W[(kc * 32 + k) * H + c4];
    }
    __syncthreads();
#pragma unroll
    for (int k = 0; k < 32; ++k) {
      float4 a0 = *(const float4*)&hsT[kc * 32 + k][r0];
      float4 a1 = *(const float4*)&hsT[kc * 32 + k][r0 + 4];
      float4 w = *(const float4*)&Ws[k][c0];
      acc[0][0] += a0.x * w.x; acc[0][1] += a0.x * w.y; acc[0][2] += a0.x * w.z; acc[0][3] += a0.x * w.w;
      acc[1][0] += a0.y * w.x; acc[1][1] += a0.y * w.y; acc[1][2] += a0.y * w.z; acc[1][3] += a0.y * w.w;
      acc[2][0] += a0.z * w.x; acc[2][1] += a0.z * w.y; acc[2][2] += a0.z * w.z; acc[2][3] += a0.z * w.w;
      acc[3][0] += a0.w * w.x; acc[3][1] += a0.w * w.y; acc[3][2] += a0.w * w.z; acc[3][3] += a0.w * w.w;
      acc[4][0] += a1.x * w.x; acc[4][1] += a1.x * w.y; acc[4][2] += a1.x * w.z; acc[4][3] += a1.x * w.w;
      acc[5][0] += a1.y * w.x; acc[5][1] += a1.y * w.y; acc[5][2] += a1.y * w.z; acc[5][3] += a1.y * w.w;
      acc[6][0] += a1.z * w.x; acc[6][1] += a1.z * w.y; acc[6][2] += a1.z * w.z; acc[6][3] += a1.z * w.w;
      acc[7][0] += a1.w * w.x; acc[7][1] += a1.w * w.y; acc[7][2] += a1.w * w.z; acc[7][3] += a1.w * w.w;
    }
  }

#pragma unroll
  for (int i = 0; i < 8; ++i) {
    int row = row0 + r0 + i;
    if (row < N) {
      ushort4 o;
      o.x = f2bf(acc[i][0]); o.y = f2bf(acc[i][1]);
      o.z = f2bf(acc[i][2]); o.w = f2bf(acc[i][3]);
      *(ushort4*)&hWb[row * H + c0] = o;
    }
  }
}

// ---------------- CSR gather: agg[n] = sum_e w_e*hW[src_e] + hW[n]/deg + bias ----------------
// 32 lanes per node, 4 channels (bf16) per lane; no atomics
__global__ __launch_bounds__(256) void gather_kernel(
    const ushort_t* __restrict__ hWb, const int2* __restrict__ csr,
    const int* __restrict__ rowptr, const float* __restrict__ dinv,
    const float* __restrict__ bias, float* __restrict__ agg)
{
  int t = blockIdx.x * 256 + threadIdx.x;
  int n = t >> 5, c4 = (t & 31) * 4;
  if (n >= N) return;
  float sw = dinv[n]; sw = sw * sw;  // 1/deg
  ushort4 us = *(const ushort4*)&hWb[n * H + c4];
  float4 bv = *(const float4*)&bias[c4];
  float4 acc = make_float4(bf2f(us.x) * sw + bv.x, bf2f(us.y) * sw + bv.y,
                           bf2f(us.z) * sw + bv.z, bf2f(us.w) * sw + bv.w);
  int e = rowptr[n], end = rowptr[n + 1];
  for (; e + 1 < end; e += 2) {
    int2 p0 = csr[e], p1 = csr[e + 1];
    float w0 = __int_as_float(p0.y), w1 = __int_as_float(p1.y);
    ushort4 u0 = *(const ushort4*)&hWb[p0.x * H + c4];
    ushort4 u1 = *(const ushort4*)&hWb[p1.x * H + c4];
    acc.x += w0 * bf2f(u0.x) + w1 * bf2f(u1.x);
    acc.y += w0 * bf2f(u0.y) + w1 * bf2f(u1.y);
    acc.z += w0 * bf2f(u0.z) + w1 * bf2f(u1.z);
    acc.w += w0 * bf2f(u0.w) + w1 * bf2f(u1.w);
  }
  if (e < end) {
    int2 p0 = csr[e];
    float w0 = __int_as_float(p0.y);
    ushort4 u0 = *(const ushort4*)&hWb[p0.x * H + c4];
    acc.x += w0 * bf2f(u0.x); acc.y += w0 * bf2f(u0.y);
    acc.z += w0 * bf2f(u0.z); acc.w += w0 * bf2f(u0.w);
  }
  *(float4*)&agg[n * H + c4] = acc;
}

// ---------------- batchnorm stats: sums[c], sums[128+c] over N rows ----------------
__global__ __launch_bounds__(256) void bn_stats_kernel(
    const float* __restrict__ a, float* __restrict__ sums)
{
  __shared__ float red[256];
  int tid = threadIdx.x;
  int c = tid & 127, half = tid >> 7;
  int r0 = blockIdx.x * 128;
  float s = 0.f, q = 0.f;
  for (int i = 0; i < 64; ++i) {
    int r = r0 + i * 2 + half;
    if (r < N) { float v = a[r * H + c]; s += v; q += v * v; }
  }
  red[tid] = s; __syncthreads();
  float s2 = (half == 0) ? s + red[tid + 128] : 0.f;
  __syncthreads();
  red[tid] = q; __syncthreads();
  if (half == 0) {
    float q2 = q + red[tid + 128];
    atomAddF(&sums[c], s2);
    atomAddF(&sums[128 + c], q2);
  }
}

// ---------------- global mean pool: chunked, run-length accumulate (batch sorted) --------
__global__ __launch_bounds__(256) void pool_kernel(
    const float* __restrict__ h, const int* __restrict__ batch,
    float* __restrict__ pooled /* pre-zeroed */)
{
  int r0 = blockIdx.x * 128;
  int rend = min(r0 + 128, N);
  int c = threadIdx.x & 127, half = threadIdx.x >> 7;
  float acc = 0.f;
  int curg = -1;
  for (int r = r0 + half; r < rend; r += 2) {
    int g = batch[r];
    if (g != curg) {
      if (curg >= 0) atomAddF(&pooled[curg * H + c], acc);
      acc = 0.f; curg = g;
    }
    acc += h[r * H + c];
  }
  if (curg >= 0) atomAddF(&pooled[curg * H + c], acc);
}

__global__ void cnt_kernel(const int* __restrict__ batch, float* __restrict__ cnt) {
  __shared__ int lb[G + 1];
  int t = threadIdx.x;  // 128 threads
  if (t <= G) {
    int lo = 0, hi = N;
    while (lo < hi) { int m = (lo + hi) >> 1; if (batch[m] < t) lo = m + 1; else hi = m; }
    lb[t] = lo;
  }
  __syncthreads();
  if (t < G) cnt[t] = (float)(lb[t + 1] - lb[t]);
}

// ---------------- head ----------------
__global__ void head1_kernel(const float* __restrict__ pooled, const float* __restrict__ cnt,
                             const float* __restrict__ W1, const float* __restrict__ b1,
                             float* __restrict__ z1)
{
  int t = blockIdx.x * 256 + threadIdx.x;  // 8192
  int g = t >> 7, c = t & 127;
  float s = 0.f;
  for (int k = 0; k < H; ++k) s += pooled[g * H + k] * W1[k * H + c];
  z1[t] = s / fmaxf(cnt[g], 1.0f) + b1[c];
}

__global__ void head_bn_kernel(float* __restrict__ z1,
                               const float* __restrict__ gamma, const float* __restrict__ beta)
{
  int c = threadIdx.x;  // 128 threads
  float s = 0.f, q = 0.f;
  for (int g = 0; g < G; ++g) { float v = z1[g * H + c]; s += v; q += v * v; }
  float mu = s / (float)G;
  float var = q / (float)G - mu * mu;
  float rs = rsqrtf(var + EPS);
  float ga = gamma[c], be = beta[c];
  for (int g = 0; g < G; ++g) {
    float v = z1[g * H + c];
    z1[g * H + c] = fmaxf((v - mu) * rs * ga + be, 0.f);
  }
}

__global__ void head2_kernel(const float* __restrict__ z1, const float* __restrict__ W2,
                             const float* __restrict__ b2, float* __restrict__ z2)
{
  int t = blockIdx.x * 256 + threadIdx.x;  // 8192
  int g = t >> 7, c = t & 127;
  float s = b2[c];
  for (int k = 0; k < H; ++k) s += z1[g * H + k] * W2[k * H + c];
  z2[t] = fmaxf(s, 0.f);
}

__global__ void head3_kernel(const float* __restrict__ z2, const float* __restrict__ W3,
                             const float* __restrict__ b3, float* __restrict__ out)
{
  int t = blockIdx.x * 256 + threadIdx.x;
  if (t < G * OUTC) {
    int g = t / OUTC, o = t % OUTC;
    float s = b3[o];
    for (int k = 0; k < H; ++k) s += z2[g * H + k] * W3[k * OUTC + o];
    out[t] = s;
  }
}

extern "C" void kernel_launch(void* const* d_in, const int* in_sizes, int n_in,
                              void* d_out, int out_size, void* d_ws, size_t ws_size,
                              hipStream_t stream) {
  const float* x     = (const float*)d_in[0];
  const int*   ei    = (const int*)d_in[1];
  const int*   srcp  = ei;
  const int*   dstp  = ei + E;
  const int*   batch = (const int*)d_in[2];
  const float* convW = (const float*)d_in[3];
  const float* convb = (const float*)d_in[4];
  const float* bng   = (const float*)d_in[5];
  const float* bnb   = (const float*)d_in[6];
  const float* W1    = (const float*)d_in[7];
  const float* b1    = (const float*)d_in[8];
  const float* hg    = (const float*)d_in[9];
  const float* hb    = (const float*)d_in[10];
  const float* W2    = (const float*)d_in[11];
  const float* b2    = (const float*)d_in[12];
  const float* W3    = (const float*)d_in[13];
  const float* b3    = (const float*)d_in[14];
  float* out = (float*)d_out;

  float*    ws     = (float*)d_ws;
  float*    agg    = ws;                           // N*H f32
  float*    dinv   = agg + (size_t)N * H;          // N
  int*      rowptr = (int*)(dinv + N);             // N+2
  int2*     csr    = (int2*)(rowptr + N + 2);      // E (8B aligned: word offset even)
  ushort_t* hWb    = (ushort_t*)(csr + E);         // N*H bf16
  int*      deg    = (int*)(hWb + (size_t)N * H);  // N   <- zero region start
  int*      cursor = deg + N;                      // N
  float*    bnsums = (float*)(cursor + N);         // (L-1)*256
  float*    pooled = bnsums + (L - 1) * 256;       // G*H (needs zero)
  float*    cnt    = pooled + G * H;               // G
  float*    z1     = cnt + G;                      // G*H
  float*    z2     = z1 + G * H;                   // G*H

  const int zero_words = N + N + (L - 1) * 256 + G * H;
  zero_kernel<<<(zero_words + 255) / 256, 256, 0, stream>>>(deg, zero_words);
  deg_count_kernel<<<(E + 255) / 256, 256, 0, stream>>>(dstp, deg);
  dinv_kernel<<<(N + 255) / 256, 256, 0, stream>>>(deg, dinv);
  scan_kernel<<<1, 1024, 0, stream>>>(deg, rowptr);
  csr_fill_kernel<<<(E + 255) / 256, 256, 0, stream>>>(srcp, dstp, dinv, rowptr, cursor, csr);
  cnt_kernel<<<1, 128, 0, stream>>>(batch, cnt);

  const float* hin = x;
  for (int l = 0; l < L; ++l) {
    const float* bs = (l == 0) ? nullptr : bnsums + (l - 1) * 256;
    const float* ga = (l == 0) ? nullptr : bng + (size_t)(l - 1) * H;
    const float* be = (l == 0) ? nullptr : bnb + (size_t)(l - 1) * H;
    gemm_layer_kernel<<<(N + 63) / 64, 256, 0, stream>>>(
        hin, convW + (size_t)l * H * H, hWb, bs, ga, be);
    gather_kernel<<<N * 32 / 256, 256, 0, stream>>>(
        hWb, csr, rowptr, dinv, convb + (size_t)l * H, agg);
    if (l < L - 1) {
      bn_stats_kernel<<<(N + 127) / 128, 256, 0, stream>>>(agg, bnsums + l * 256);
      hin = agg;
    }
  }

  pool_kernel<<<(N + 127) / 128, 256, 0, stream>>>(agg, batch, pooled);
  head1_kernel<<<32, 256, 0, stream>>>(pooled, cnt, W1, b1, z1);
  head_bn_kernel<<<1, 128, 0, stream>>>(z1, hg, hb);
  head2_kernel<<<32, 256, 0, stream>>>(z1, W2, b2, z2);
  head3_kernel<<<3, 256, 0, stream>>>(z2, W3, b3, out);
}